// Round 2
// baseline (172.175 us; speedup 1.0000x reference)
//
#include <hip/hip_runtime.h>

// HMM forward, LINEAR domain, power-of-2 rescaling. B=64 chains, D=128 steps,
// A=128 states.
//   p_{t+1}[j] = (sum_k w[k] * E[t][k][j]) * eBC[b][t][j] * f_t
//
// R2: SINGLE-WAVE-PER-CHAIN, BARRIER-FREE fwd. 64 blocks x 64 threads.
// Lane l owns j = 2l, 2l+1 (adjacent pair -> one packed fp16 uint).
// Per step:
//   - cross-lane exchange: 1 ds_write_b32 (own pair) + 16 broadcast
//     ds_read_b128 (all 128 w's) -- intra-wave, lgkmcnt-ordered, NO s_barrier.
//   - dots: full K=128 per lane: 128 v_dot2 (fp32 accum), 8 indep chains.
//   - E[t] per lane = 512B, relaid by prep so the wave's 32
//     global_load_dwordx4 are each 1KB fully-coalesced; double-buffered in
//     VGPRs (2x128 regs), prefetched 1 step ahead (step ~500cy >> L2 ~300cy).
//     __launch_bounds__(64,1) -> up to 512 VGPRs.
//   - rescale f = 2^-floor(log2 max w): 6-DPP wave max of own fp32 v0,v1 +
//     exponent-field bit trick; runs parallel to dots (off critical path).
//     Exponent accumulates in int Eacc; final L = Phi0 + ln2*Eacc + log(sum).
// E'' layout (uints, per t: 8192): a = q*256 + l*4 + c, q = jsel*16+ic,
//   value = pack(e(2i,j), e(2i+1,j)), i = 4*ic+c, j = 2*l+jsel.
// fwd lane l reads uint4 at t*32768 + q*1024 + l*16; component c <-> kpair
// 4*ic+c pairs with LDS w-uint 4*ic+c (lane 4ic+c's packed pair). q<16 -> j=2l
// (accs a0..a3), q>=16 -> j=2l+1 (accs b0..b3).

#define B_ 64
#define D_ 128
#define A_ 128
#define T_ 127

// ws layout (4-byte units), ~8.32 MB
#define E16_UINTS (T_ * 8192)      // [t][q][l][c] uints (consumption order)
#define BC_OFF E16_UINTS           // [b][t][j] fp32 = exp(bern log-prob)
#define BC_SZ (B_ * T_ * A_)
#define LP_OFF (BC_OFF + BC_SZ)    // log_p_a1[j] fp32

typedef _Float16 h2 __attribute__((ext_vector_type(2)));

__device__ __forceinline__ int packrtz(float a, float b) {
    auto p = __builtin_amdgcn_cvt_pkrtz(a, b); // low=a, high=b
    return __builtin_bit_cast(int, p);
}
__device__ __forceinline__ float dot2acc(unsigned int e, unsigned int s, float acc) {
    return __builtin_amdgcn_fdot2(__builtin_bit_cast(h2, e),
                                  __builtin_bit_cast(h2, s), acc, false);
}

template <int CTRL>
__device__ __forceinline__ float dpp_mov_self(float x) {
    return __int_as_float(__builtin_amdgcn_update_dpp(
        __float_as_int(x), __float_as_int(x), CTRL, 0xF, 0xF, false));
}
template <int CTRL>
__device__ __forceinline__ float dpp_mov_zero(float x) {
    return __int_as_float(__builtin_amdgcn_update_dpp(
        0, __float_as_int(x), CTRL, 0xF, 0xF, true));
}
__device__ __forceinline__ float wave_max_bcast(float x) {
    x = fmaxf(x, dpp_mov_self<0x111>(x));
    x = fmaxf(x, dpp_mov_self<0x112>(x));
    x = fmaxf(x, dpp_mov_self<0x114>(x));
    x = fmaxf(x, dpp_mov_self<0x118>(x));
    x = fmaxf(x, dpp_mov_self<0x142>(x));
    x = fmaxf(x, dpp_mov_self<0x143>(x));
    return __int_as_float(__builtin_amdgcn_readlane(__float_as_int(x), 63));
}
__device__ __forceinline__ float wave_sum_bcast(float x) {
    x += dpp_mov_zero<0x111>(x);
    x += dpp_mov_zero<0x112>(x);
    x += dpp_mov_zero<0x114>(x);
    x += dpp_mov_zero<0x118>(x);
    x += dpp_mov_zero<0x142>(x);
    x += dpp_mov_zero<0x143>(x);
    return __int_as_float(__builtin_amdgcn_readlane(__float_as_int(x), 63));
}

// ---------------- single merged prep kernel: 127 blocks x 256 ----------------
__global__ __launch_bounds__(256) void prep(const float* __restrict__ uT,
                                            const float* __restrict__ u1,
                                            const float* __restrict__ x,
                                            const float* __restrict__ lg,
                                            float* __restrict__ ws,
                                            float* __restrict__ out) {
    __shared__ float Zl[A_];
    const int t = blockIdx.x, tid = threadIdx.x;
    const int wave = tid >> 6, lane = tid & 63;
    const float* u = uT + (size_t)t * A_ * A_;

    // Z[k] = lse_j u[k][j], wave-parallel per row
    for (int rr = 0; rr < 32; rr++) {
        int r = wave * 32 + rr;
        float a = u[r * A_ + lane];
        float c = u[r * A_ + lane + 64];
        float mx = wave_max_bcast(fmaxf(a, c));
        float s = wave_sum_bcast(__expf(a - mx) + __expf(c - mx));
        if (lane == 0) Zl[r] = mx + __logf(s);
    }
    __syncthreads();

    // E'' store in fwd consumption order (see header comment)
    unsigned int* Et = (unsigned int*)ws + (size_t)t * 8192;
    for (int it = 0; it < 32; it++) {
        int a = it * 256 + tid;     // 0..8191
        int c = a & 3, l = (a >> 2) & 63, q = a >> 8;
        int jsel = q >> 4, ic = q & 15;
        int i = 4 * ic + c, j = 2 * l + jsel;
        float e0 = __expf(u[(2 * i) * A_ + j] - Zl[2 * i]);
        float e1 = __expf(u[(2 * i + 1) * A_ + j] - Zl[2 * i + 1]);
        Et[a] = (unsigned int)packrtz(e0, e1);
    }

    // eBC[b][t][j] = exp(bern(x[b][t+1], j)) = sigmoid(+-l)
    {
        int j = tid & 127, hb = tid >> 7;
        float lv = lg[(t + 1) * A_ + j];
        float sg = 1.f / (1.f + __expf(-lv));   // P(x=1)
        float g1 = sg, g0 = 1.f - sg;           // P(x=0)
        float* BC = ws + BC_OFF;
        for (int b = hb * 32; b < hb * 32 + 32; b++) {
            float xv = x[b * D_ + t + 1];
            BC[((size_t)b * T_ + t) * A_ + j] = (xv != 0.f) ? g1 : g0;
        }
    }

    // block 0, wave 0: log_softmax(u1) -> LP + output 1
    if (t == 0 && wave == 0) {
        float a = u1[lane], c = u1[lane + 64];
        float mx = wave_max_bcast(fmaxf(a, c));
        float s = wave_sum_bcast(__expf(a - mx) + __expf(c - mx));
        float lse = mx + __logf(s);
        ws[LP_OFF + lane] = a - lse;
        ws[LP_OFF + lane + 64] = c - lse;
        out[B_ * A_ + lane] = a - lse;
        out[B_ * A_ + lane + 64] = c - lse;
    }
}

// ---------------- main: 64 blocks x 64 threads (1 wave), NO barriers --------
#define STEP(T, EC, EN, BCC, BCN, DOPF)                                       \
    {                                                                         \
        /* scale from this step's input w (fp32 copies) -- off critical path*/\
        float mx_ = wave_max_bcast(fmaxf(v0, v1));                            \
        unsigned eb_ = (__float_as_uint(mx_) >> 23) & 255u;                   \
        float f_ = __uint_as_float((254u - eb_) << 23); /* 2^(127-eb) */      \
        Eacc += (int)eb_ - 127;                                               \
        if (DOPF) { /* prefetch E[T+1] into free buffer + next bc */          \
            const uint4* pf_ = (const uint4*)(Eb + (size_t)((T) + 1) * 32768);\
            _Pragma("unroll") for (int q = 0; q < 32; q++) EN[q] = pf_[q*64]; \
            BCN = *(const float2*)(BCg + ((T) + 1) * A_);                     \
            __builtin_amdgcn_sched_barrier(0); /* pin loads here (no sink) */ \
        }                                                                     \
        uint4 ew_[16];                                                        \
        _Pragma("unroll") for (int r = 0; r < 16; r++) ew_[r] = ewl4[r];      \
        float a0=0, a1=0, a2=0, a3=0, b0=0, b1=0, b2=0, b3=0;                 \
        _Pragma("unroll") for (int r = 0; r < 16; r++) {                      \
            a0 = dot2acc(EC[r].x, ew_[r].x, a0);                              \
            a1 = dot2acc(EC[r].y, ew_[r].y, a1);                              \
            a2 = dot2acc(EC[r].z, ew_[r].z, a2);                              \
            a3 = dot2acc(EC[r].w, ew_[r].w, a3);                              \
            b0 = dot2acc(EC[16 + r].x, ew_[r].x, b0);                         \
            b1 = dot2acc(EC[16 + r].y, ew_[r].y, b1);                         \
            b2 = dot2acc(EC[16 + r].z, ew_[r].z, b2);                         \
            b3 = dot2acc(EC[16 + r].w, ew_[r].w, b3);                         \
        }                                                                     \
        float S0 = (a0 + a1) + (a2 + a3);                                     \
        float S1 = (b0 + b1) + (b2 + b3);                                     \
        v0 = S0 * ((BCC).x * f_);                                             \
        v1 = S1 * ((BCC).y * f_);                                             \
        ewl[l] = (unsigned)packrtz(v0, v1);                                   \
    }

__global__ __launch_bounds__(64, 1) void fwd(const float* __restrict__ x,
                                             const float* __restrict__ lg,
                                             const float* __restrict__ ws,
                                             float* __restrict__ out) {
    __shared__ __align__(16) unsigned ewl[64];
    const uint4* ewl4 = (const uint4*)ewl;
    const int b = blockIdx.x, l = threadIdx.x;    // 64 threads = 1 wave

    const char* Eb = (const char*)ws + (size_t)l * 16;
    const float* BCg = ws + BC_OFF + (size_t)b * T_ * A_ + 2 * l; // + t*A_
    const float* LP = ws + LP_OFF;

    // init v_0[j] = log_p_a1[j] + bern(x[b][0], j), j = 2l, 2l+1 (log domain)
    float2 lg2 = *(const float2*)(lg + 2 * l);
    float2 lp2 = *(const float2*)(LP + 2 * l);
    float xv0 = x[b * D_];
    float sp0 = (lg2.x > 0.f) ? (lg2.x + log1pf(__expf(-lg2.x)))
                              : log1pf(__expf(lg2.x));
    float sp1 = (lg2.y > 0.f) ? (lg2.y + log1pf(__expf(-lg2.y)))
                              : log1pf(__expf(lg2.y));
    float vl0 = lp2.x + ((xv0 != 0.f) ? (lg2.x - sp0) : (-sp0));
    float vl1 = lp2.y + ((xv0 != 0.f) ? (lg2.y - sp1) : (-sp1));
    float Phi0 = wave_max_bcast(fmaxf(vl0, vl1));
    float v0 = __expf(vl0 - Phi0);
    float v1 = __expf(vl1 - Phi0);
    int Eacc = 0;
    ewl[l] = (unsigned)packrtz(v0, v1);

    uint4 EA[32], EB[32];
    float2 bc0, bc1;
    {   // preload t=0 -> EA, bc[0]
        const uint4* p0 = (const uint4*)Eb;
#pragma unroll
        for (int q = 0; q < 32; q++) EA[q] = p0[q * 64];
        bc0 = *(const float2*)(BCg);
        __builtin_amdgcn_sched_barrier(0);
    }
    bc1 = bc0;

    for (int t = 0; t < 126; t += 2) {  // steps 0..125
        STEP(t + 0, EA, EB, bc0, bc1, 1)
        STEP(t + 1, EB, EA, bc1, bc0, 1)
    }
    STEP(126, EA, EB, bc0, bc1, 0)

    // final: L = Phi0 + ln2*Eacc + log(sum_j w_127[j])
    float sw = wave_sum_bcast(v0 + v1);
    float L = Phi0 + 0.69314718056f * (float)Eacc + __logf(sw);
    out[b * A_ + l] = L;
    out[b * A_ + l + 64] = L;
}

extern "C" void kernel_launch(void* const* d_in, const int* in_sizes, int n_in,
                              void* d_out, int out_size, void* d_ws, size_t ws_size,
                              hipStream_t stream) {
    const float* x = (const float*)d_in[0];    // [B,D]
    const float* u1 = (const float*)d_in[1];   // [1,1,1,A]
    const float* uT = (const float*)d_in[2];   // [D-1,A,A]
    const float* lg = (const float*)d_in[3];   // [1,D,1,A]
    float* ws = (float*)d_ws;                  // ~8.32 MB
    float* out = (float*)d_out;

    prep<<<dim3(T_), dim3(256), 0, stream>>>(uT, u1, x, lg, ws, out);
    fwd<<<dim3(B_), dim3(64), 0, stream>>>(x, lg, ws, out);
}

// Round 3
// 160.841 us; speedup vs baseline: 1.0705x; 1.0705x over previous
//
#include <hip/hip_runtime.h>

// HMM forward, LINEAR domain, power-of-2 rescaling, BATCHED-MFMA. B=64
// chains, D=128 steps, A=128 states.
// Key insight (R3): all chains share E[t] -> step t is a [64x128]x[128x128]
// GEMM, not 64 independent matvecs. 4 blocks x 16 chains x 4 waves; per
// step per wave: 8 x v_mfma_f32_16x16x32_f16 (M=16 chains, N=32 j-cols per
// wave, K=128 in 4 chunks). This amortizes the per-step sync/LDS latency
// (R1: 1390cy/step for ONE chain) over 16 chains.
//   Vnew[b][j] = (sum_k V[b][k] E[t][k][j]) * bern(x[b][t+1],j) * f_t
// - V (fp16) in LDS ping-pong, XOR-swizzled: byte = m*256 +
//   (((k>>3)^m)&15)*16 + (k&7)*2 -> A-frag ds_read_b128 and C writeback
//   ~conflict-free. A-frag: lane l: row m=l&15, k = kc*32+(l>>4)*8+e.
// - E staged by prep in B-frag order: lane l frag(n,kc) = 8 consecutive k
//   fp16 at col j=32w+16n+(l&15); 8 coalesced dwordx4/lane/step, VGPR
//   double-buffered, prefetched 1 step ahead (64 regs -> no spill, unlike R2).
// - BCh: prep pre-selects bern prob by x (fp16, per chain) in C-layout order:
//   one dwordx4/lane/step. Replaces BC stream + bit machinery.
// - scale f = 2^-e(M), M = global max, DELAYED one step via Mb[2][4] LDS
//   ping-pong (per-wave maxes written pre-barrier, combined after) -- off
//   critical path. Exponents accumulate in Eacc; L = Phi0 + ln2*Eacc +
//   log(sum_j V127[b][j]).
// - ONE lgkm-only barrier per step (raw s_barrier; vmem prefetch stays in
//   flight across it).

#define B_ 64
#define D_ 128
#define A_ 128
#define T_ 127

// ws layout (4-byte units), ~6.25 MB
#define E_UINTS (T_ * 8192)              // [t][chunk][lane][word] uints
#define BCH_OFF E_UINTS                  // [t][cb][w][lane][8 fp16]
#define LP_OFF (BCH_OFF + T_ * 4096)     // log_p_a1[j] fp32

typedef _Float16 f16x8 __attribute__((ext_vector_type(8)));
typedef float f32x4 __attribute__((ext_vector_type(4)));

__device__ __forceinline__ int packrtz(float a, float b) {
    auto p = __builtin_amdgcn_cvt_pkrtz(a, b); // low=a, high=b
    return __builtin_bit_cast(int, p);
}

template <int CTRL>
__device__ __forceinline__ float dpp_mov_self(float x) {
    return __int_as_float(__builtin_amdgcn_update_dpp(
        __float_as_int(x), __float_as_int(x), CTRL, 0xF, 0xF, false));
}
template <int CTRL>
__device__ __forceinline__ float dpp_mov_zero(float x) {
    return __int_as_float(__builtin_amdgcn_update_dpp(
        0, __float_as_int(x), CTRL, 0xF, 0xF, true));
}
__device__ __forceinline__ float wave_max_bcast(float x) {
    x = fmaxf(x, dpp_mov_self<0x111>(x));
    x = fmaxf(x, dpp_mov_self<0x112>(x));
    x = fmaxf(x, dpp_mov_self<0x114>(x));
    x = fmaxf(x, dpp_mov_self<0x118>(x));
    x = fmaxf(x, dpp_mov_self<0x142>(x));
    x = fmaxf(x, dpp_mov_self<0x143>(x));
    return __int_as_float(__builtin_amdgcn_readlane(__float_as_int(x), 63));
}
__device__ __forceinline__ float wave_sum_bcast(float x) {
    x += dpp_mov_zero<0x111>(x);
    x += dpp_mov_zero<0x112>(x);
    x += dpp_mov_zero<0x114>(x);
    x += dpp_mov_zero<0x118>(x);
    x += dpp_mov_zero<0x142>(x);
    x += dpp_mov_zero<0x143>(x);
    return __int_as_float(__builtin_amdgcn_readlane(__float_as_int(x), 63));
}

__device__ __forceinline__ f32x4 mfma16(uint4 a, uint4 b, f32x4 c) {
    return __builtin_amdgcn_mfma_f32_16x16x32_f16(
        __builtin_bit_cast(f16x8, a), __builtin_bit_cast(f16x8, b), c, 0, 0, 0);
}

// ---------------- single merged prep kernel: 127 blocks x 256 ----------------
__global__ __launch_bounds__(256) void prep(const float* __restrict__ uT,
                                            const float* __restrict__ u1,
                                            const float* __restrict__ x,
                                            const float* __restrict__ lg,
                                            float* __restrict__ ws,
                                            float* __restrict__ out) {
    __shared__ float Zl[A_];
    const int t = blockIdx.x, tid = threadIdx.x;
    const int wave = tid >> 6, lane = tid & 63;
    const float* u = uT + (size_t)t * A_ * A_;

    // Z[k] = lse_j u[k][j], wave-parallel per row
    for (int rr = 0; rr < 32; rr++) {
        int r = wave * 32 + rr;
        float a = u[r * A_ + lane];
        float c = u[r * A_ + lane + 64];
        float mx = wave_max_bcast(fmaxf(a, c));
        float s = wave_sum_bcast(__expf(a - mx) + __expf(c - mx));
        if (lane == 0) Zl[r] = mx + __logf(s);
    }
    __syncthreads();

    // E in fwd B-frag chunk order; u reads fully coalesced (row pairs).
    // uint idx = (w*8+n*4+kc)*256 + lane*4 + word;
    // packs E[k0][j],E[k0+1][j]; k0 = kc*32+(lane>>4)*8+word*2, j = 32w+16n+(lane&15)
    {
        unsigned* Et = (unsigned*)ws + (size_t)t * 8192;
        const int j = tid & 127, kh = tid >> 7;
        const int wj = j >> 5, nj = (j >> 4) & 1, loj = j & 15;
        for (int it = 0; it < 32; it++) {
            int kp = it * 2 + kh;       // k-pair index 0..63
            int k0 = kp * 2;
            float e0 = __expf(u[k0 * A_ + j] - Zl[k0]);
            float e1 = __expf(u[k0 * A_ + A_ + j] - Zl[k0 + 1]);
            int kc = kp >> 4, g = (kp >> 2) & 3, wd = kp & 3;
            int idx = ((wj * 8 + nj * 4 + kc) << 8) + (g * 16 + loj) * 4 + wd;
            Et[idx] = (unsigned)packrtz(e0, e1);
        }
    }

    // BCh[t][cb][w][lane][h], h = n*4+r: bern prob (x-selected, fp16) for
    // chain cb*16+(lane>>4)*4+r, col j = 32w+16n+(lane&15), at step t (x[.,t+1])
    {
        unsigned* BH = (unsigned*)ws + BCH_OFF + (size_t)t * 4096;
        for (int it = 0; it < 4; it++) {
            int cell = it * 256 + tid;                 // 0..1023
            int cbb = cell >> 8, wc = (cell >> 6) & 3, ln = cell & 63;
            int lgc = ln >> 4, loc = ln & 15;
            int j0 = 32 * wc + loc, j1 = j0 + 16;
            float lv0 = lg[(t + 1) * A_ + j0], lv1 = lg[(t + 1) * A_ + j1];
            float sg0 = 1.f / (1.f + __expf(-lv0));
            float sg1 = 1.f / (1.f + __expf(-lv1));
            float hv[8];
#pragma unroll
            for (int r = 0; r < 4; r++) {
                float xv = x[(cbb * 16 + lgc * 4 + r) * D_ + t + 1];
                hv[r] = (xv != 0.f) ? sg0 : 1.f - sg0;
                hv[4 + r] = (xv != 0.f) ? sg1 : 1.f - sg1;
            }
            uint4 o;
            o.x = (unsigned)packrtz(hv[0], hv[1]);
            o.y = (unsigned)packrtz(hv[2], hv[3]);
            o.z = (unsigned)packrtz(hv[4], hv[5]);
            o.w = (unsigned)packrtz(hv[6], hv[7]);
            *(uint4*)(BH + cell * 4) = o;
        }
    }

    // block 0, wave 0: log_softmax(u1) -> LP + output 1
    if (t == 0 && wave == 0) {
        float a = u1[lane], c = u1[lane + 64];
        float mx = wave_max_bcast(fmaxf(a, c));
        float s = wave_sum_bcast(__expf(a - mx) + __expf(c - mx));
        float lse = mx + __logf(s);
        ws[LP_OFF + lane] = a - lse;
        ws[LP_OFF + lane + 64] = c - lse;
        out[B_ * A_ + lane] = a - lse;
        out[B_ * A_ + lane + 64] = c - lse;
    }
}

// ---------------- main: 4 blocks x 256 (4 waves), 1 raw barrier/step --------
#define BARRIER() asm volatile("s_waitcnt lgkmcnt(0)\n\ts_barrier" ::: "memory")

#define STEP(T, PAR, EC, EP, BCC, BCP, DOPF)                                   \
    {                                                                          \
        uint4 af0 = *(const uint4*)((const char*)&Vs[PAR][0] + ard[0]);        \
        uint4 af1 = *(const uint4*)((const char*)&Vs[PAR][0] + ard[1]);        \
        uint4 af2 = *(const uint4*)((const char*)&Vs[PAR][0] + ard[2]);        \
        uint4 af3 = *(const uint4*)((const char*)&Vs[PAR][0] + ard[3]);        \
        float4 mb4 = *(const float4*)&Mb[PAR][0];                              \
        __builtin_amdgcn_sched_barrier(0); /* LDS reads issue first */         \
        if (DOPF) { /* prefetch step T+1 (in flight across barrier) */         \
            const uint4* pf_ = (const uint4*)(Ebp + (size_t)((T) + 1) * 32768);\
            _Pragma("unroll") for (int i = 0; i < 8; i++) EP[i] = pf_[i * 64]; \
            BCP = *(const uint4*)(BChp + (size_t)((T) + 1) * 16384);           \
            __builtin_amdgcn_sched_barrier(0); /* pin loads here (no sink) */  \
        }                                                                      \
        f32x4 ac0 = {0.f, 0.f, 0.f, 0.f}, ac1 = {0.f, 0.f, 0.f, 0.f};          \
        ac0 = mfma16(af0, EC[0], ac0);                                         \
        ac1 = mfma16(af0, EC[4], ac1);                                         \
        ac0 = mfma16(af1, EC[1], ac0);                                         \
        ac1 = mfma16(af1, EC[5], ac1);                                         \
        ac0 = mfma16(af2, EC[2], ac0);                                         \
        ac1 = mfma16(af2, EC[6], ac1);                                         \
        ac0 = mfma16(af3, EC[3], ac0);                                         \
        ac1 = mfma16(af3, EC[7], ac1);                                         \
        float M = fmaxf(fmaxf(mb4.x, mb4.y), fmaxf(mb4.z, mb4.w));             \
        unsigned eb = (__float_as_uint(M) >> 23) & 255u;                       \
        float f = __uint_as_float((254u - eb) << 23); /* 2^(127-eb) */         \
        Eacc += (int)eb - 127;                                                 \
        f16x8 bcv = __builtin_bit_cast(f16x8, BCC);                            \
        float o0 = ac0[0] * ((float)bcv[0] * f);                               \
        float o1 = ac0[1] * ((float)bcv[1] * f);                               \
        float o2 = ac0[2] * ((float)bcv[2] * f);                               \
        float o3 = ac0[3] * ((float)bcv[3] * f);                               \
        float o4 = ac1[0] * ((float)bcv[4] * f);                               \
        float o5 = ac1[1] * ((float)bcv[5] * f);                               \
        float o6 = ac1[2] * ((float)bcv[6] * f);                               \
        float o7 = ac1[3] * ((float)bcv[7] * f);                               \
        char* Vw = (char*)&Vs[(PAR) ^ 1][0];                                   \
        *(_Float16*)(Vw + wad[0]) = (_Float16)o0;                              \
        *(_Float16*)(Vw + wad[1]) = (_Float16)o1;                              \
        *(_Float16*)(Vw + wad[2]) = (_Float16)o2;                              \
        *(_Float16*)(Vw + wad[3]) = (_Float16)o3;                              \
        *(_Float16*)(Vw + wad[4]) = (_Float16)o4;                              \
        *(_Float16*)(Vw + wad[5]) = (_Float16)o5;                              \
        *(_Float16*)(Vw + wad[6]) = (_Float16)o6;                              \
        *(_Float16*)(Vw + wad[7]) = (_Float16)o7;                              \
        float mx8 = fmaxf(fmaxf(fmaxf(o0, o1), fmaxf(o2, o3)),                 \
                          fmaxf(fmaxf(o4, o5), fmaxf(o6, o7)));                \
        float Mw = wave_max_bcast(mx8);                                        \
        if (l == 0) Mb[(PAR) ^ 1][w] = Mw;                                     \
        BARRIER();                                                             \
    }

__global__ __launch_bounds__(256, 1) void fwd(const float* __restrict__ x,
                                              const float* __restrict__ lg,
                                              const float* __restrict__ ws,
                                              float* __restrict__ out) {
    __shared__ __align__(16) unsigned short Vs[2][2048]; // [2][16 rows][128 k]
    __shared__ __align__(16) float Mb[2][4];
    __shared__ float red4[4];
    __shared__ float Lrow[16];
    const int cb = blockIdx.x, tid = threadIdx.x;
    const int w = tid >> 6, l = tid & 63;
    const int lgq = l >> 4, lo = l & 15;

    // ---- init: Vs[0] = exp(vlog - Phi0), vlog = LP + bern(x[b][0]) ----
    {
        const int bm = tid >> 4;           // chain-in-block 0..15
        const int jb = (tid & 15) * 8;
        const float* LP = ws + LP_OFF;
        float xv0 = x[(cb * 16 + bm) * D_];
        float vl[8];
        float mloc = -1e30f;
#pragma unroll
        for (int e = 0; e < 8; e++) {
            float lv = lg[jb + e];
            float sp = (lv > 0.f) ? (lv + log1pf(__expf(-lv)))
                                  : log1pf(__expf(lv));
            float v = LP[jb + e] + ((xv0 != 0.f) ? (lv - sp) : (-sp));
            vl[e] = v;
            mloc = fmaxf(mloc, v);
        }
        float mwv = wave_max_bcast(mloc);
        if (l == 0) red4[w] = mwv;
        __syncthreads();
        float Phi0_ = fmaxf(fmaxf(red4[0], red4[1]), fmaxf(red4[2], red4[3]));
        uint4 pv;
        pv.x = (unsigned)packrtz(__expf(vl[0] - Phi0_), __expf(vl[1] - Phi0_));
        pv.y = (unsigned)packrtz(__expf(vl[2] - Phi0_), __expf(vl[3] - Phi0_));
        pv.z = (unsigned)packrtz(__expf(vl[4] - Phi0_), __expf(vl[5] - Phi0_));
        pv.w = (unsigned)packrtz(__expf(vl[6] - Phi0_), __expf(vl[7] - Phi0_));
        *(uint4*)((char*)&Vs[0][0] + bm * 256 + ((tid & 15) ^ bm) * 16) = pv;
        if (tid < 4) Mb[0][tid] = 1.0f;
        red4[0] = Phi0_;   // park for later (re-read after loop is racy-free:
        __syncthreads();   // nothing else writes red4)
    }
    const float Phi0 = red4[0];

    // step-invariant addresses (XOR-swizzled V layout)
    int ard[4];
#pragma unroll
    for (int kc = 0; kc < 4; kc++)
        ard[kc] = lo * 256 + (((kc * 4 + lgq) ^ lo)) * 16;
    int wad[8];
#pragma unroll
    for (int n = 0; n < 2; n++)
#pragma unroll
        for (int r = 0; r < 4; r++) {
            int m = lgq * 4 + r;
            wad[n * 4 + r] = m * 256 +
                (((w * 4 + n * 2 + (lo >> 3)) ^ m) & 15) * 16 + (lo & 7) * 2;
        }

    const char* Ebp = (const char*)ws + w * 8192 + l * 16;
    const char* BChp = (const char*)ws + (size_t)BCH_OFF * 4 + cb * 4096 +
                       w * 1024 + l * 16;

    // preload t=0
    uint4 EA[8], EB[8], bchA, bchB;
    {
        const uint4* p0 = (const uint4*)Ebp;
#pragma unroll
        for (int i = 0; i < 8; i++) EA[i] = p0[i * 64];
        bchA = *(const uint4*)BChp;
        __builtin_amdgcn_sched_barrier(0);
    }
    bchB = bchA;
    int Eacc = 0;
    BARRIER();   // init Vs/Mb visible; prefetch stays in flight

    for (int t = 0; t < 126; t += 2) {
        STEP(t, 0, EA, EB, bchA, bchB, 1)
        STEP(t + 1, 1, EB, EA, bchB, bchA, 1)
    }
    STEP(126, 0, EA, EB, bchA, bchB, 0)

    // ---- final: L_b = Phi0 + ln2*Eacc + log(sum_j V127[b][j]) ----
    if (tid < 16) {
        const uint4* row = (const uint4*)((const char*)&Vs[1][0] + tid * 256);
        float s = 0.f;
#pragma unroll
        for (int q = 0; q < 16; q++) {
            f16x8 hv = __builtin_bit_cast(f16x8, row[q]);
            float t0 = 0.f;
#pragma unroll
            for (int e = 0; e < 8; e++) t0 += (float)hv[e];
            s += t0;
        }
        Lrow[tid] = Phi0 + 0.69314718055994531f * (float)Eacc + __logf(s);
    }
    __syncthreads();
    float Lv = Lrow[tid >> 4];
    float4 ov = {Lv, Lv, Lv, Lv};
    float* op = out + (size_t)(cb * 16 + (tid >> 4)) * A_ + (tid & 15) * 8;
    *(float4*)op = ov;
    *(float4*)(op + 4) = ov;
}

extern "C" void kernel_launch(void* const* d_in, const int* in_sizes, int n_in,
                              void* d_out, int out_size, void* d_ws, size_t ws_size,
                              hipStream_t stream) {
    const float* x = (const float*)d_in[0];    // [B,D]
    const float* u1 = (const float*)d_in[1];   // [1,1,1,A]
    const float* uT = (const float*)d_in[2];   // [D-1,A,A]
    const float* lg = (const float*)d_in[3];   // [1,D,1,A]
    float* ws = (float*)d_ws;                  // ~6.25 MB used
    float* out = (float*)d_out;

    prep<<<dim3(T_), dim3(256), 0, stream>>>(uT, u1, x, lg, ws, out);
    fwd<<<dim3(4), dim3(256), 0, stream>>>(x, lg, ws, out);
}